// Round 7
// baseline (230.608 us; speedup 1.0000x reference)
//
#include <hip/hip_runtime.h>
#include <hip/hip_bf16.h>

#define N_NODES 50000
#define N_EDGES 312500
#define WIDTH   256
#define LN_EPS  1e-5f
#define NB_SCAN 196   // ceil(50000/256)

typedef __attribute__((ext_vector_type(8))) short bf16x8;
typedef __attribute__((ext_vector_type(4))) float f32x4;

__device__ __forceinline__ float bf_lo(unsigned u) { return __uint_as_float(u << 16); }
__device__ __forceinline__ float bf_hi(unsigned u) { return __uint_as_float(u & 0xffff0000u); }

__device__ __forceinline__ bf16x8 cvt8(float4 a, float4 b) {
    union { __hip_bfloat16 hh[8]; bf16x8 v; } u;
    u.hh[0] = __float2bfloat16(a.x); u.hh[1] = __float2bfloat16(a.y);
    u.hh[2] = __float2bfloat16(a.z); u.hh[3] = __float2bfloat16(a.w);
    u.hh[4] = __float2bfloat16(b.x); u.hh[5] = __float2bfloat16(b.y);
    u.hh[6] = __float2bfloat16(b.z); u.hh[7] = __float2bfloat16(b.w);
    return u.v;
}

// ---------------------------------------------------------------------------
// CSR build: count -> 3-pass parallel scan -> fill (packed with dinv[src])
// NOTE: single-block scan_all was tried in R4: 107us (one CU, 255 idle).
// ---------------------------------------------------------------------------
__global__ void count_dst(const int* __restrict__ dst, int* __restrict__ counts, int e) {
    int i = blockIdx.x * blockDim.x + threadIdx.x;
    if (i < e) atomicAdd(&counts[dst[i]], 1);
}

__global__ __launch_bounds__(256) void scan_pass_a(const int* __restrict__ counts,
                                                   int* __restrict__ block_sums, int n) {
    int t = threadIdx.x;
    int i = blockIdx.x * 256 + t;
    int v = (i < n) ? counts[i] : 0;
    #pragma unroll
    for (int off = 32; off > 0; off >>= 1) v += __shfl_down(v, off, 64);
    __shared__ int ws[4];
    if ((t & 63) == 0) ws[t >> 6] = v;
    __syncthreads();
    if (t == 0) block_sums[blockIdx.x] = ws[0] + ws[1] + ws[2] + ws[3];
}

__global__ __launch_bounds__(256) void scan_pass_b(int* __restrict__ block_sums, int nb) {
    int t = threadIdx.x;
    int lane = t & 63, w = t >> 6;
    int v = (t < nb) ? block_sums[t] : 0;
    int inc = v;
    #pragma unroll
    for (int off = 1; off < 64; off <<= 1) {
        int u = __shfl_up(inc, off, 64);
        if (lane >= off) inc += u;
    }
    __shared__ int wsum[4];
    if (lane == 63) wsum[w] = inc;
    __syncthreads();
    int woff = 0;
    for (int k = 0; k < 4; k++) if (k < w) woff += wsum[k];
    if (t < nb) block_sums[t] = inc - v + woff;  // exclusive
}

__global__ __launch_bounds__(256) void scan_pass_c(int* __restrict__ counts,   // in: counts, out: cursor
                                                   const int* __restrict__ block_sums,
                                                   int* __restrict__ offsets,
                                                   float* __restrict__ dinv, int n) {
    int t = threadIdx.x;
    int i = blockIdx.x * 256 + t;
    int lane = t & 63, w = t >> 6;
    int v = (i < n) ? counts[i] : 0;
    int inc = v;
    #pragma unroll
    for (int off = 1; off < 64; off <<= 1) {
        int u = __shfl_up(inc, off, 64);
        if (lane >= off) inc += u;
    }
    __shared__ int wsum[4];
    if (lane == 63) wsum[w] = inc;
    __syncthreads();
    int woff = 0;
    for (int k = 0; k < 4; k++) if (k < w) woff += wsum[k];
    int excl = block_sums[blockIdx.x] + inc - v + woff;
    if (i < n) {
        offsets[i] = excl;
        counts[i]  = excl;                       // cursor starts at offset
        dinv[i]    = rsqrtf((float)(v + 1));     // +1 self-loop
    }
    if (i == n - 1) offsets[n] = N_EDGES;
}

// csr2[pos] = {src, bits(dinv[src])}
__global__ void fill_csr(const int* __restrict__ src, const int* __restrict__ dst,
                         const float* __restrict__ dinv,
                         int* __restrict__ cursor, int2* __restrict__ csr2, int e) {
    int i = blockIdx.x * blockDim.x + threadIdx.x;
    if (i < e) {
        int s = src[i];
        int pos = atomicAdd(&cursor[dst[i]], 1);
        csr2[pos] = make_int2(s, __float_as_int(dinv[s]));
    }
}

// ---------------------------------------------------------------------------
// Direct-fragment MFMA GEMM (NO LDS, no barriers).
// h[m][nc] = sum_k x[m][k] * W[nc][k], bf16-rounded inputs, fp32 acc.
// Each lane loads A/B fragments straight from global in MFMA layout:
//   A[m=lane&15][k=quad*8..+8] -> 2 float4 per frag, converted in regs.
// A-row L2 reuse (x4 across wn waves and blockIdx.y) is cheap (L2 ~34 TB/s).
// K accumulation order identical to the staged version -> bit-identical h.
// ---------------------------------------------------------------------------
__global__ __launch_bounds__(256) void gemm_mfma(const float* __restrict__ x,
                                                 const float* __restrict__ W,
                                                 __hip_bfloat16* __restrict__ h) {
    const int t    = threadIdx.x;
    const int lane = t & 63;
    const int wv   = t >> 6;
    const int wm   = wv & 1;
    const int wn   = wv >> 1;
    const int lrow = lane & 15;
    const int quad = lane >> 4;
    const int mrow0 = blockIdx.x * 128;
    const int ncol0 = blockIdx.y * 128;

    const float* aptr[4];
    #pragma unroll
    for (int i = 0; i < 4; i++) {
        int gr = mrow0 + wm * 64 + i * 16 + lrow;
        gr = min(gr, N_NODES - 1);           // tail clamp; garbage rows not stored
        aptr[i] = x + (size_t)gr * WIDTH + quad * 8;
    }
    const float* bptr[4];
    #pragma unroll
    for (int j = 0; j < 4; j++) {
        int gc = ncol0 + wn * 64 + j * 16 + lrow;   // always < 256
        bptr[j] = W + (size_t)gc * WIDTH + quad * 8;
    }

    f32x4 acc[4][4];
    #pragma unroll
    for (int i = 0; i < 4; i++)
        #pragma unroll
        for (int j = 0; j < 4; j++)
            #pragma unroll
            for (int r = 0; r < 4; r++) acc[i][j][r] = 0.0f;

    #pragma unroll 2
    for (int kc = 0; kc < 8; kc++) {         // 8 chunks of K=32
        int k0 = kc * 32;
        bf16x8 af[4], bfr[4];
        #pragma unroll
        for (int i = 0; i < 4; i++) {
            float4 f0 = *(const float4*)(aptr[i] + k0);
            float4 f1 = *(const float4*)(aptr[i] + k0 + 4);
            af[i] = cvt8(f0, f1);
        }
        #pragma unroll
        for (int j = 0; j < 4; j++) {
            float4 g0 = *(const float4*)(bptr[j] + k0);
            float4 g1 = *(const float4*)(bptr[j] + k0 + 4);
            bfr[j] = cvt8(g0, g1);
        }
        #pragma unroll
        for (int i = 0; i < 4; i++)
            #pragma unroll
            for (int j = 0; j < 4; j++)
                acc[i][j] = __builtin_amdgcn_mfma_f32_16x16x32_bf16(
                    af[i], bfr[j], acc[i][j], 0, 0, 0);
    }

    #pragma unroll
    for (int i = 0; i < 4; i++) {
        #pragma unroll
        for (int j = 0; j < 4; j++) {
            int col = ncol0 + wn * 64 + j * 16 + lrow;
            #pragma unroll
            for (int r = 0; r < 4; r++) {
                int gr = mrow0 + wm * 64 + i * 16 + quad * 4 + r;
                if (gr < N_NODES)
                    h[(size_t)gr * WIDTH + col] = __float2bfloat16(acc[i][j][r]);
            }
        }
    }
}

// ---------------------------------------------------------------------------
// Fused gather + self-loop + bias + LayerNorm + ReLU.
// One wave per dst node; lane l owns cols 4l..4l+3. Inner loop unrolled x8
// so 8 independent row loads are in flight (hide L2/L3/HBM latency).
// ---------------------------------------------------------------------------
__global__ __launch_bounds__(256) void gather_ln(const __hip_bfloat16* __restrict__ h,
                                                 const float* __restrict__ dinv,
                                                 const int* __restrict__ offsets,
                                                 const int2* __restrict__ csr2,
                                                 const float* __restrict__ b,
                                                 const float* __restrict__ gamma,
                                                 const float* __restrict__ beta,
                                                 float* __restrict__ out) {
    const int lane = threadIdx.x & 63;
    const int d    = blockIdx.x * 4 + (threadIdx.x >> 6);

    const uint2* hrows = (const uint2*)h;        // 64 uint2 per row
    int beg = offsets[d], end = offsets[d + 1];
    float dv = dinv[d];

    uint2 hv = hrows[(size_t)d * 64 + lane];
    float a0 = dv * bf_lo(hv.x), a1 = dv * bf_hi(hv.x);
    float a2 = dv * bf_lo(hv.y), a3 = dv * bf_hi(hv.y);

    for (int base = beg; base < end; base += 64) {
        int cnt = min(end - base, 64);
        int   s  = 0;
        float sv = 0.0f;
        if (lane < cnt) {
            int2 p = csr2[base + lane];
            s  = p.x;
            sv = __int_as_float(p.y);
        }
        int q = 0;
        for (; q + 8 <= cnt; q += 8) {
            int   si[8]; float wi[8]; uint2 ri[8];
            #pragma unroll
            for (int u = 0; u < 8; u++) {
                si[u] = __shfl(s, q + u, 64);
                wi[u] = __shfl(sv, q + u, 64);
            }
            #pragma unroll
            for (int u = 0; u < 8; u++)
                ri[u] = hrows[(size_t)si[u] * 64 + lane];
            #pragma unroll
            for (int u = 0; u < 8; u++) {
                a0 += wi[u] * bf_lo(ri[u].x); a1 += wi[u] * bf_hi(ri[u].x);
                a2 += wi[u] * bf_lo(ri[u].y); a3 += wi[u] * bf_hi(ri[u].y);
            }
        }
        for (; q < cnt; q++) {
            int   sq  = __shfl(s, q, 64);
            float svq = __shfl(sv, q, 64);
            uint2 rv  = hrows[(size_t)sq * 64 + lane];
            a0 += svq * bf_lo(rv.x);
            a1 += svq * bf_hi(rv.x);
            a2 += svq * bf_lo(rv.y);
            a3 += svq * bf_hi(rv.y);
        }
    }

    float4 bv = *(const float4*)(b + lane * 4);
    float v0 = bv.x + dv * a0;
    float v1 = bv.y + dv * a1;
    float v2 = bv.z + dv * a2;
    float v3 = bv.w + dv * a3;

    float s1 = v0 + v1 + v2 + v3;
    float s2 = v0 * v0 + v1 * v1 + v2 * v2 + v3 * v3;
    #pragma unroll
    for (int off = 32; off > 0; off >>= 1) {
        s1 += __shfl_xor(s1, off, 64);
        s2 += __shfl_xor(s2, off, 64);
    }
    float mu   = s1 * (1.0f / 256.0f);
    float var  = s2 * (1.0f / 256.0f) - mu * mu;
    float rstd = rsqrtf(var + LN_EPS);

    float4 gv = *(const float4*)(gamma + lane * 4);
    float4 bt = *(const float4*)(beta + lane * 4);
    float4 y;
    y.x = fmaxf((v0 - mu) * rstd * gv.x + bt.x, 0.0f);
    y.y = fmaxf((v1 - mu) * rstd * gv.y + bt.y, 0.0f);
    y.z = fmaxf((v2 - mu) * rstd * gv.z + bt.z, 0.0f);
    y.w = fmaxf((v3 - mu) * rstd * gv.w + bt.w, 0.0f);
    *(float4*)(out + (size_t)d * WIDTH + lane * 4) = y;
}

// ---------------------------------------------------------------------------
extern "C" void kernel_launch(void* const* d_in, const int* in_sizes, int n_in,
                              void* d_out, int out_size, void* d_ws, size_t ws_size,
                              hipStream_t stream) {
    const float* x     = (const float*)d_in[0];
    const int*   ei    = (const int*)d_in[1];   // [2, E] flat: src then dst
    const float* W     = (const float*)d_in[2];
    const float* b     = (const float*)d_in[3];
    const float* gamma = (const float*)d_in[4];
    const float* beta  = (const float*)d_in[5];
    float* out = (float*)d_out;

    const int* src = ei;
    const int* dst = ei + N_EDGES;

    const int n = N_NODES, e = N_EDGES;

    // workspace layout (4-byte word offsets):
    //   dinv    [0, 50048)
    //   h       [50048, 6450048)     bf16, 12.8M elems (6.4M words)
    //   counts  [6450048, 6500048)   -> cursor after scan
    //   offsets [6500048, 6550052)
    //   bsums   [6550052, 6550308)
    //   csr2    [6550310, ...)       int2 per edge, 8B aligned
    float* wsf = (float*)d_ws;
    float*          dinv       = wsf;
    __hip_bfloat16* h          = (__hip_bfloat16*)(wsf + 50048);
    int*            counts     = (int*)(wsf + 6450048);
    int*            offsets    = (int*)(wsf + 6500048);
    int*            block_sums = (int*)(wsf + 6550052);
    int2*           csr2       = (int2*)(wsf + 6550310);

    hipMemsetAsync(counts, 0, n * sizeof(int), stream);

    count_dst  <<<(e + 255) / 256, 256, 0, stream>>>(dst, counts, e);
    scan_pass_a<<<NB_SCAN, 256, 0, stream>>>(counts, block_sums, n);
    scan_pass_b<<<1, 256, 0, stream>>>(block_sums, NB_SCAN);
    scan_pass_c<<<NB_SCAN, 256, 0, stream>>>(counts, block_sums, offsets, dinv, n);
    fill_csr   <<<(e + 255) / 256, 256, 0, stream>>>(src, dst, dinv, counts, csr2, e);

    dim3 ggrid((N_NODES + 127) / 128, 2);
    gemm_mfma<<<ggrid, 256, 0, stream>>>(x, W, h);

    gather_ln<<<n / 4, 256, 0, stream>>>(h, dinv, offsets, csr2, b, gamma, beta, out);
}